// Round 13
// baseline (68.824 us; speedup 1.0000x reference)
//
#include <hip/hip_runtime.h>

#define T_SEQ 2048
#define DIMM 512
#define NH 8
#define HD 64
#define BB 2
#define CHUNK 64
#define NCHUNK 32
#define EPSV 1e-6f
#define LDST 72    // bf16 LDS row stride (shorts) for the small kernels
#define PCST 258   // proj256 bounce-tile row stride (shorts), conflict-free cols
#define PJ_LDS 132096  // bytes: max(2*32768*2 staging, 256*258*2 bounce)

typedef __attribute__((ext_vector_type(8))) short bf16x8;
typedef __attribute__((ext_vector_type(4))) short s16x4;
typedef __attribute__((ext_vector_type(4))) float f32x4;

static __device__ inline short f2bf(float f) {
    union { float f; unsigned u; } v; v.f = f;
    unsigned r = v.u + 0x7FFFu + ((v.u >> 16) & 1u);
    return (short)(r >> 16);
}
static __device__ inline float bf2f(short s) {
    union { unsigned u; float f; } v; v.u = ((unsigned)(unsigned short)s) << 16;
    return v.f;
}
static __device__ __forceinline__ void gload_lds16(const void* g, void* l) {
    __builtin_amdgcn_global_load_lds(
        (__attribute__((address_space(1))) void*)g,
        (__attribute__((address_space(3))) void*)l, 16, 0, 0);
}

// ---------------------------------------------------------------------------
// Kernel 0: fp32 -> bf16. x -> xb; {Wq,Wk,Wv} -> Wcat[1536][512]; Wo -> Wob.
// grid 1536, block 256
// ---------------------------------------------------------------------------
__global__ __launch_bounds__(256) void convert_kernel(
    const float* __restrict__ x, const float* __restrict__ Wq,
    const float* __restrict__ Wk, const float* __restrict__ Wv,
    const float* __restrict__ Wo,
    short* __restrict__ xb, short* __restrict__ Wcat, short* __restrict__ Wob)
{
    const int u = blockIdx.x * 256 + threadIdx.x;
    const float* src; short* dst;
    if (u < 262144) {
        src = x + (size_t)u * 8; dst = xb + (size_t)u * 8;
    } else {
        const int v = u - 262144;
        const int o = (v & 32767) * 8;
        if (v < 32768)       { src = Wq + o; dst = Wcat + o; }
        else if (v < 65536)  { src = Wk + o; dst = Wcat + 262144 + o; }
        else if (v < 98304)  { src = Wv + o; dst = Wcat + 524288 + o; }
        else                 { src = Wo + o; dst = Wob + o; }
    }
    const float4 a = *(const float4*)src;
    const float4 b = *(const float4*)(src + 4);
    *(bf16x8*)dst = (bf16x8){f2bf(a.x), f2bf(a.y), f2bf(a.z), f2bf(a.w),
                             f2bf(b.x), f2bf(b.y), f2bf(b.z), f2bf(b.w)};
}

// ---------------------------------------------------------------------------
// Kernel 1: 256x256-tile 8-wave QKV projection (m198-style 4-phase/K-tile).
// C[4096][1536] = xb @ Wcat^T; per block: 256 rows x 256 cols (= 4 heads of
// one of Q/K/V). Epilogue: softmax->Qs / elu->Kbf+Ktb / Vt.
// grid (16, 6), block 512, 132 KB dynamic LDS.
// ---------------------------------------------------------------------------
__global__ __launch_bounds__(512) void proj256_kernel(
    const short* __restrict__ xb, const short* __restrict__ Wcat,
    short* __restrict__ Qs, short* __restrict__ Kbf,
    short* __restrict__ Ktb, short* __restrict__ Vt)
{
    extern __shared__ short S[];   // slot s: A at s*32768, B at s*32768+16384
    const int m0 = blockIdx.x * 256;
    const int n0 = blockIdx.y * 256;
    const int which = blockIdx.y >> 1;        // 0=Q 1=K 2=V
    const int headbase = (blockIdx.y & 1) * 4;
    const int tid = threadIdx.x;
    const int lane = tid & 63, w = tid >> 6;  // 8 waves
    const int wr = w >> 2, wc = w & 3;        // wave grid 2(M) x 4(N)
    const int fr = lane & 15, fg = lane >> 4;
    const int xr = fr & 7;
    const int l8 = lane >> 3;                 // 0..7
    const int sw8 = ((lane & 7) ^ l8) * 8;    // source-preswizzled k-chunk
    const int b = m0 >> 11, t0 = m0 & (T_SEQ - 1);

    f32x4 acc[8][4] = {};

    // stage one half-tile (2 gload_lds/thread): half 0/1 = A rows 0-127/128-255,
    // half 2/3 = B rows 0-127/128-255 of K-tile ktv into slot ds.
    #define STAGE_HALF(ds, ktv, half) do {                                        \
        const int isB_ = (half) >> 1, hb_ = ((half) & 1) * 128;                   \
        short* dst_ = S + (ds) * 32768 + isB_ * 16384 + (hb_ + w * 16) * 64;      \
        const short* g_ = isB_ ? (Wcat + (size_t)(n0 + hb_ + w * 16) * DIMM)      \
                               : (xb + (size_t)(m0 + hb_ + w * 16) * DIMM);       \
        gload_lds16(g_ + (size_t)l8 * DIMM + (ktv) * 64 + sw8, dst_);             \
        gload_lds16(g_ + (size_t)(8 + l8) * DIMM + (ktv) * 64 + sw8, dst_ + 512); \
    } while (0)

    // prologue: K-tile 0 into slot 0
    STAGE_HALF(0, 0, 0); STAGE_HALF(0, 0, 1); STAGE_HALF(0, 0, 2); STAGE_HALF(0, 0, 3);

    for (int kt = 0; kt < 8; ++kt) {
        const int slot = kt & 1;
        const short* Ab = S + slot * 32768;
        const short* Bb = Ab + 16384;
        // entry: kt's staged data must have landed (issued >= 2 phases ago, except kt=0)
        asm volatile("s_waitcnt vmcnt(0)" ::: "memory");
        __builtin_amdgcn_s_barrier();

        bf16x8 bfrag[4], af[4];
        // ---- phase 0: B(ks0) + A(i0-3, ks0); stage next A-halves ----
        #pragma unroll
        for (int j = 0; j < 4; j++)
            bfrag[j] = *(const bf16x8*)&Bb[(wc * 64 + j * 16 + fr) * 64 + (fg ^ xr) * 8];
        #pragma unroll
        for (int i = 0; i < 4; i++)
            af[i] = *(const bf16x8*)&Ab[(wr * 128 + i * 16 + fr) * 64 + (fg ^ xr) * 8];
        if (kt < 7) { STAGE_HALF(slot ^ 1, kt + 1, 0); STAGE_HALF(slot ^ 1, kt + 1, 1); }
        __builtin_amdgcn_s_setprio(1);
        #pragma unroll
        for (int i = 0; i < 4; i++)
            #pragma unroll
            for (int j = 0; j < 4; j++)
                acc[i][j] = __builtin_amdgcn_mfma_f32_16x16x32_bf16(af[i], bfrag[j], acc[i][j], 0, 0, 0);
        __builtin_amdgcn_s_setprio(0);
        __builtin_amdgcn_s_barrier();
        // ---- phase 1: A(i4-7, ks0); stage next B-halves ----
        #pragma unroll
        for (int i = 0; i < 4; i++)
            af[i] = *(const bf16x8*)&Ab[(wr * 128 + (i + 4) * 16 + fr) * 64 + (fg ^ xr) * 8];
        if (kt < 7) { STAGE_HALF(slot ^ 1, kt + 1, 2); STAGE_HALF(slot ^ 1, kt + 1, 3); }
        __builtin_amdgcn_s_setprio(1);
        #pragma unroll
        for (int i = 0; i < 4; i++)
            #pragma unroll
            for (int j = 0; j < 4; j++)
                acc[i + 4][j] = __builtin_amdgcn_mfma_f32_16x16x32_bf16(af[i], bfrag[j], acc[i + 4][j], 0, 0, 0);
        __builtin_amdgcn_s_setprio(0);
        __builtin_amdgcn_s_barrier();
        // ---- phase 2: B(ks1) + A(i0-3, ks1) ----
        #pragma unroll
        for (int j = 0; j < 4; j++)
            bfrag[j] = *(const bf16x8*)&Bb[(wc * 64 + j * 16 + fr) * 64 + ((4 + fg) ^ xr) * 8];
        #pragma unroll
        for (int i = 0; i < 4; i++)
            af[i] = *(const bf16x8*)&Ab[(wr * 128 + i * 16 + fr) * 64 + ((4 + fg) ^ xr) * 8];
        __builtin_amdgcn_s_setprio(1);
        #pragma unroll
        for (int i = 0; i < 4; i++)
            #pragma unroll
            for (int j = 0; j < 4; j++)
                acc[i][j] = __builtin_amdgcn_mfma_f32_16x16x32_bf16(af[i], bfrag[j], acc[i][j], 0, 0, 0);
        __builtin_amdgcn_s_setprio(0);
        __builtin_amdgcn_s_barrier();
        // ---- phase 3: A(i4-7, ks1) ----
        #pragma unroll
        for (int i = 0; i < 4; i++)
            af[i] = *(const bf16x8*)&Ab[(wr * 128 + (i + 4) * 16 + fr) * 64 + ((4 + fg) ^ xr) * 8];
        __builtin_amdgcn_s_setprio(1);
        #pragma unroll
        for (int i = 0; i < 4; i++)
            #pragma unroll
            for (int j = 0; j < 4; j++)
                acc[i + 4][j] = __builtin_amdgcn_mfma_f32_16x16x32_bf16(af[i], bfrag[j], acc[i + 4][j], 0, 0, 0);
        __builtin_amdgcn_s_setprio(0);
        __builtin_amdgcn_s_barrier();
    }
    #undef STAGE_HALF
    __syncthreads();   // drain everything before reusing S as the bounce tile

    // dump acc -> Cs[256][PCST] (elu+1 fused for K)
    short* Cs = S;
    #pragma unroll
    for (int i = 0; i < 8; i++)
        #pragma unroll
        for (int j = 0; j < 4; j++)
            #pragma unroll
            for (int reg = 0; reg < 4; reg++) {
                float val = acc[i][j][reg];
                if (which == 1) val = (val > 0.f) ? (val + 1.f) : __expf(val);
                Cs[(wr * 128 + i * 16 + fg * 4 + reg) * PCST + wc * 64 + j * 16 + fr] = f2bf(val);
            }
    __syncthreads();

    if (which == 0) {
        // softmax per (row, head-local): 1024 tasks over 512 threads
        #pragma unroll
        for (int rep = 0; rep < 2; rep++) {
            const int task = rep * 512 + tid;
            const int row = task & 255, hl = task >> 8;
            const int head = headbase + hl;
            const unsigned* cr = (const unsigned*)&Cs[row * PCST + hl * 64];
            unsigned u[32];
            #pragma unroll
            for (int s = 0; s < 32; s++) u[s] = cr[s];
            float mx = -1e30f;
            #pragma unroll
            for (int s = 0; s < 32; s++) {
                mx = fmaxf(mx, bf2f((short)(u[s] & 0xffff)));
                mx = fmaxf(mx, bf2f((short)(u[s] >> 16)));
            }
            float sum = 0.f;
            #pragma unroll
            for (int s = 0; s < 32; s++) {
                sum += __expf(bf2f((short)(u[s] & 0xffff)) - mx);
                sum += __expf(bf2f((short)(u[s] >> 16)) - mx);
            }
            const float inv = 1.f / sum;
            short* qp = Qs + (((size_t)(b * NH + head)) * T_SEQ + t0 + row) * HD;
            #pragma unroll
            for (int g = 0; g < 8; g++) {
                bf16x8 o;
                #pragma unroll
                for (int k = 0; k < 4; k++) {
                    const unsigned uv = u[g * 4 + k];
                    o[2 * k]     = f2bf(__expf(bf2f((short)(uv & 0xffff)) - mx) * inv);
                    o[2 * k + 1] = f2bf(__expf(bf2f((short)(uv >> 16)) - mx) * inv);
                }
                *(bf16x8*)(qp + g * 8) = o;
            }
        }
    } else if (which == 1) {
        // Kbf row copies (already elu'd)
        #pragma unroll
        for (int rep = 0; rep < 2; rep++) {
            const int task = rep * 512 + tid;
            const int row = task & 255, hl = task >> 8;
            const int head = headbase + hl;
            const unsigned* cr = (const unsigned*)&Cs[row * PCST + hl * 64];
            short* kp = Kbf + (((size_t)(b * NH + head)) * T_SEQ + t0 + row) * HD;
            #pragma unroll
            for (int g = 0; g < 8; g++) {
                bf16x8 o;
                #pragma unroll
                for (int k = 0; k < 4; k++) {
                    const unsigned uv = cr[g * 4 + k];
                    o[2 * k]     = (short)(uv & 0xffff);
                    o[2 * k + 1] = (short)(uv >> 16);
                }
                *(bf16x8*)(kp + g * 8) = o;
            }
        }
        // Ktb transpose: thread -> (col, row-half of 128)
        {
            const int col = tid & 255, rh = tid >> 8;
            const int head = headbase + (col >> 6), d = col & 63;
            short* ktp = Ktb + (((size_t)(b * NH + head)) * HD + d) * T_SEQ + t0 + rh * 128;
            #pragma unroll
            for (int s = 0; s < 16; s++) {
                bf16x8 o;
                #pragma unroll
                for (int k = 0; k < 8; k++) o[k] = Cs[(rh * 128 + s * 8 + k) * PCST + col];
                *(bf16x8*)(ktp + s * 8) = o;
            }
        }
    } else {
        // Vt transpose
        const int col = tid & 255, rh = tid >> 8;
        const int head = headbase + (col >> 6), e = col & 63;
        short* vtp = Vt + (((size_t)(b * NH + head)) * HD + e) * T_SEQ + t0 + rh * 128;
        #pragma unroll
        for (int s = 0; s < 16; s++) {
            bf16x8 o;
            #pragma unroll
            for (int k = 0; k < 8; k++) o[k] = Cs[(rh * 128 + s * 8 + k) * PCST + col];
            *(bf16x8*)(vtp + s * 8) = o;
        }
    }
}

// ---------------------------------------------------------------------------
// Kernel 2: per-chunk sums via MFMA: S[e][d] = sum_t Vt[e][t]*Kt[d][t]; ksum[d].
// grid 512, block 256
// ---------------------------------------------------------------------------
__global__ __launch_bounds__(256) void chunk_sum_kernel(
    const short* __restrict__ Ktb, const short* __restrict__ Vt,
    float* __restrict__ Schunk, float* __restrict__ kchunk)
{
    __shared__ short VtL[64 * LDST];
    __shared__ short KtL[64 * LDST];
    __shared__ float ksp[4][64];
    const int bh = blockIdx.x >> 5, c = blockIdx.x & 31;
    const int tid = threadIdx.x;
    const int lane = tid & 63, w = tid >> 6;
    const int fr = lane & 15, fg = lane >> 4;
    #pragma unroll
    for (int it = 0; it < 2; it++) {
        const int qi = it * 256 + tid;
        const int r = qi >> 3, c8 = (qi & 7) * 8;
        *(bf16x8*)&VtL[r * LDST + c8] =
            *(const bf16x8*)(Vt + ((size_t)(bh * HD) + r) * T_SEQ + c * CHUNK + c8);
        *(bf16x8*)&KtL[r * LDST + c8] =
            *(const bf16x8*)(Ktb + ((size_t)(bh * HD) + r) * T_SEQ + c * CHUNK + c8);
    }
    __syncthreads();
    f32x4 acc[4] = {};
    #pragma unroll
    for (int ks = 0; ks < 2; ks++) {
        const bf16x8 av = *(const bf16x8*)&VtL[(w * 16 + fr) * LDST + ks * 32 + fg * 8];
        #pragma unroll
        for (int j = 0; j < 4; j++) {
            const bf16x8 bk = *(const bf16x8*)&KtL[(j * 16 + fr) * LDST + ks * 32 + fg * 8];
            acc[j] = __builtin_amdgcn_mfma_f32_16x16x32_bf16(av, bk, acc[j], 0, 0, 0);
        }
    }
    float* Sout = Schunk + ((size_t)bh * NCHUNK + c) * 4096;
    #pragma unroll
    for (int j = 0; j < 4; j++)
        #pragma unroll
        for (int reg = 0; reg < 4; reg++)
            Sout[(w * 16 + fg * 4 + reg) * 64 + j * 16 + fr] = acc[j][reg];
    float ps = 0.f;
    #pragma unroll
    for (int t = 0; t < 16; t++) ps += bf2f(KtL[lane * LDST + w * 16 + t]);
    ksp[w][lane] = ps;
    __syncthreads();
    if (tid < 64)
        kchunk[((size_t)bh * NCHUNK + c) * 64 + tid] =
            ksp[0][tid] + ksp[1][tid] + ksp[2][tid] + ksp[3][tid];
}

// ---------------------------------------------------------------------------
// Kernel 3: exclusive prefix over 32 chunks; one scan per thread. grid 260
// ---------------------------------------------------------------------------
__global__ __launch_bounds__(256) void scan_kernel(float* __restrict__ Schunk,
                                                   float* __restrict__ kchunk)
{
    const int gid = blockIdx.x * 256 + threadIdx.x;
    if (blockIdx.x < 256) {
        const int bh = gid >> 12, i = gid & 4095;
        float run = 0.f;
        float* p = Schunk + (size_t)bh * NCHUNK * 4096 + i;
        for (int c = 0; c < NCHUNK; c++) { const float tv = p[c * 4096]; p[c * 4096] = run; run += tv; }
    } else {
        const int idx = gid - 65536;
        const int bh = idx >> 6, d = idx & 63;
        float run = 0.f;
        float* p = kchunk + (size_t)bh * NCHUNK * 64 + d;
        for (int c = 0; c < NCHUNK; c++) { const float tv = p[c * 64]; p[c * 64] = run; run += tv; }
    }
}

// ---------------------------------------------------------------------------
// Kernel 4: intra-chunk via MFMA.
// qn = Qs/(Ksum+eps); A = tril(qn.K^T); attn = qn.Sp^T + A.V^T  (bf16 out)
// grid 512, block 256
// ---------------------------------------------------------------------------
__global__ __launch_bounds__(256) void intra_kernel(
    const short* __restrict__ Qs, const short* __restrict__ Kbf,
    const short* __restrict__ Vt, const float* __restrict__ Schunk,
    const float* __restrict__ kchunk, short* __restrict__ attnb)
{
    __shared__ short B1[64 * LDST];
    __shared__ short B2[64 * LDST];
    __shared__ short KL[64 * LDST];
    __shared__ short VtL[64 * LDST];
    __shared__ short QnL[64 * LDST];
    __shared__ float gsum[4][64];
    __shared__ float kpre[64];
    const int bh = blockIdx.x >> 5, c = blockIdx.x & 31;
    const int tid = threadIdx.x;
    const int lane = tid & 63, w = tid >> 6;
    const int fr = lane & 15, fg = lane >> 4;
    const size_t tdbase = ((size_t)bh * T_SEQ + c * CHUNK) * HD;
    #pragma unroll
    for (int it = 0; it < 2; it++) {
        const int qi = it * 256 + tid;
        const int r = qi >> 3, c8 = (qi & 7) * 8;
        *(bf16x8*)&B1[r * LDST + c8]  = *(const bf16x8*)(Qs + tdbase + r * HD + c8);
        *(bf16x8*)&KL[r * LDST + c8]  = *(const bf16x8*)(Kbf + tdbase + r * HD + c8);
        *(bf16x8*)&VtL[r * LDST + c8] =
            *(const bf16x8*)(Vt + ((size_t)(bh * HD) + r) * T_SEQ + c * CHUNK + c8);
    }
    {
        const float* Sp = Schunk + ((size_t)bh * NCHUNK + c) * 4096;
        #pragma unroll
        for (int it = 0; it < 4; it++) {
            const int qi = it * 256 + tid;
            const int r = qi >> 4, c4 = (qi & 15) * 4;
            const float4 v = *(const float4*)(Sp + r * 64 + c4);
            *(s16x4*)&B2[r * LDST + c4] = (s16x4){f2bf(v.x), f2bf(v.y), f2bf(v.z), f2bf(v.w)};
        }
    }
    if (tid < 64) kpre[tid] = kchunk[((size_t)bh * NCHUNK + c) * 64 + tid];
    __syncthreads();
    {
        float s = 0.f;
        #pragma unroll
        for (int t = 0; t < 16; t++) s += bf2f(KL[(w * 16 + t) * LDST + lane]);
        gsum[w][lane] = s;
    }
    __syncthreads();
    {
        float run = kpre[lane];
        for (int gg = 0; gg < w; gg++) run += gsum[gg][lane];
        #pragma unroll
        for (int t0 = 0; t0 < 16; t0++) {
            const int t = w * 16 + t0;
            run += bf2f(KL[t * LDST + lane]);
            const float qv = bf2f(B1[t * LDST + lane]);
            QnL[t * LDST + lane] = f2bf(qv / (run + EPSV));
        }
    }
    __syncthreads();
    {
        f32x4 a1[4] = {};
        #pragma unroll
        for (int ks = 0; ks < 2; ks++) {
            const bf16x8 aq = *(const bf16x8*)&QnL[(w * 16 + fr) * LDST + ks * 32 + fg * 8];
            #pragma unroll
            for (int j = 0; j < 4; j++) {
                const bf16x8 bk = *(const bf16x8*)&KL[(j * 16 + fr) * LDST + ks * 32 + fg * 8];
                a1[j] = __builtin_amdgcn_mfma_f32_16x16x32_bf16(aq, bk, a1[j], 0, 0, 0);
            }
        }
        const int trow = w * 16 + fg * 4;
        #pragma unroll
        for (int j = 0; j < 4; j++)
            #pragma unroll
            for (int reg = 0; reg < 4; reg++) {
                const int t = trow + reg, s = j * 16 + fr;
                B1[t * LDST + s] = (s <= t) ? f2bf(a1[j][reg]) : (short)0;
            }
    }
    __syncthreads();
    {
        f32x4 a2[4] = {};
        #pragma unroll
        for (int ks = 0; ks < 2; ks++) {
            const bf16x8 aq = *(const bf16x8*)&QnL[(w * 16 + fr) * LDST + ks * 32 + fg * 8];
            const bf16x8 aa = *(const bf16x8*)&B1[(w * 16 + fr) * LDST + ks * 32 + fg * 8];
            #pragma unroll
            for (int j = 0; j < 4; j++) {
                const bf16x8 bs = *(const bf16x8*)&B2[(j * 16 + fr) * LDST + ks * 32 + fg * 8];
                const bf16x8 bv = *(const bf16x8*)&VtL[(j * 16 + fr) * LDST + ks * 32 + fg * 8];
                a2[j] = __builtin_amdgcn_mfma_f32_16x16x32_bf16(aq, bs, a2[j], 0, 0, 0);
                a2[j] = __builtin_amdgcn_mfma_f32_16x16x32_bf16(aa, bv, a2[j], 0, 0, 0);
            }
        }
        short* ap = attnb + tdbase;
        const int trow = w * 16 + fg * 4;
        #pragma unroll
        for (int j = 0; j < 4; j++)
            #pragma unroll
            for (int reg = 0; reg < 4; reg++)
                ap[(trow + reg) * HD + j * 16 + fr] = f2bf(a2[j][reg]);
    }
}

// ---------------------------------------------------------------------------
// Kernel 5: out = attn(permuted) @ Wo^T + bo, 64x64 tile. grid (64,8), 256
// ---------------------------------------------------------------------------
__global__ __launch_bounds__(256) void outproj_mfma_kernel(
    const short* __restrict__ attnb, const short* __restrict__ Wob,
    const float* __restrict__ bo, float* __restrict__ out)
{
    __shared__ short As[64 * 64];
    __shared__ short Bs[64 * 64];
    const int m0 = blockIdx.x * 64;
    const int n0 = blockIdx.y * 64;
    const int tid = threadIdx.x;
    const int lane = tid & 63, w = tid >> 6;
    const int fr = lane & 15, fg = lane >> 4;
    const int lr = lane >> 3, lc = (lane & 7) * 8;
    const int b = m0 >> 11, tbase = m0 & (T_SEQ - 1);
    f32x4 acc[4] = {};
    for (int k0 = 0; k0 < DIMM; k0 += 64) {
        const int h = k0 >> 6;
        #pragma unroll
        for (int it = 0; it < 2; it++) {
            const int r0 = w * 16 + it * 8;
            gload_lds16(attnb + (((size_t)(b * NH + h)) * T_SEQ + tbase + r0 + lr) * HD + lc,
                        &As[r0 * 64]);
            gload_lds16(Wob + (size_t)(n0 + r0 + lr) * DIMM + k0 + lc, &Bs[r0 * 64]);
        }
        __syncthreads();
        #pragma unroll
        for (int ks = 0; ks < 2; ks++) {
            const bf16x8 af = *(const bf16x8*)&As[(w * 16 + fr) * 64 + ks * 32 + fg * 8];
            #pragma unroll
            for (int j = 0; j < 4; j++) {
                const bf16x8 bfr = *(const bf16x8*)&Bs[(j * 16 + fr) * 64 + ks * 32 + fg * 8];
                acc[j] = __builtin_amdgcn_mfma_f32_16x16x32_bf16(af, bfr, acc[j], 0, 0, 0);
            }
        }
        __syncthreads();
    }
    #pragma unroll
    for (int j = 0; j < 4; j++)
        #pragma unroll
        for (int reg = 0; reg < 4; reg++) {
            const int m = m0 + w * 16 + fg * 4 + reg;
            const int n = n0 + j * 16 + fr;
            out[(size_t)m * DIMM + n] = acc[j][reg] + bo[n];
        }
}

// ---------------------------------------------------------------------------
extern "C" void kernel_launch(void* const* d_in, const int* in_sizes, int n_in,
                              void* d_out, int out_size, void* d_ws, size_t ws_size,
                              hipStream_t stream)
{
    const float* x  = (const float*)d_in[0];
    const float* Wq = (const float*)d_in[1];
    const float* Wk = (const float*)d_in[2];
    const float* Wv = (const float*)d_in[3];
    const float* Wo = (const float*)d_in[4];
    const float* bo = (const float*)d_in[5];
    float* out = (float*)d_out;

    const size_t NELEM = (size_t)BB * T_SEQ * DIMM;   // 2,097,152
    short* xb    = (short*)d_ws;                      // [4096][512]
    short* Wcat  = xb + NELEM;                        // [1536][512]
    short* Wob   = Wcat + 786432;                     // [512][512]
    short* Qs    = Wob + 262144;
    short* Kbf   = Qs + NELEM;
    short* Ktb   = Kbf + NELEM;
    short* Vt    = Ktb + NELEM;
    short* attnb = Vt + NELEM;
    float* Schunk = (float*)(attnb + NELEM);                    // [bh][c][e][d]
    float* kchunk = Schunk + (size_t)BB * NH * NCHUNK * 4096;   // [bh][c][d]

    static bool attr_set = false;
    if (!attr_set) {
        hipFuncSetAttribute((const void*)proj256_kernel,
                            hipFuncAttributeMaxDynamicSharedMemorySize, PJ_LDS);
        attr_set = true;
    }

    convert_kernel<<<dim3(1536), 256, 0, stream>>>(x, Wq, Wk, Wv, Wo, xb, Wcat, Wob);
    proj256_kernel<<<dim3(16, 6), 512, PJ_LDS, stream>>>(xb, Wcat, Qs, Kbf, Ktb, Vt);
    chunk_sum_kernel<<<dim3(BB * NH * NCHUNK), 256, 0, stream>>>(Ktb, Vt, Schunk, kchunk);
    scan_kernel<<<dim3(260), 256, 0, stream>>>(Schunk, kchunk);
    intra_kernel<<<dim3(BB * NH * NCHUNK), 256, 0, stream>>>(Qs, Kbf, Vt, Schunk, kchunk, attnb);
    outproj_mfma_kernel<<<dim3(64, 8), 256, 0, stream>>>(attnb, Wob, bo, out);
}

// Round 14
// 68.714 us; speedup vs baseline: 1.0016x; 1.0016x over previous
//
#include <hip/hip_runtime.h>

#define T_SEQ 2048
#define DIMM 512
#define NH 8
#define HD 64
#define BB 2
#define CHUNK 64
#define NCHUNK 32
#define EPSV 1e-6f
#define LDST 72    // bf16 LDS row stride (shorts) for the small kernels
#define BCST 66    // proj bounce-tile row stride (shorts)

typedef __attribute__((ext_vector_type(8))) short bf16x8;
typedef __attribute__((ext_vector_type(4))) short s16x4;
typedef __attribute__((ext_vector_type(4))) float f32x4;

static __device__ inline short f2bf(float f) {
    union { float f; unsigned u; } v; v.f = f;
    unsigned r = v.u + 0x7FFFu + ((v.u >> 16) & 1u);
    return (short)(r >> 16);
}
static __device__ inline float bf2f(short s) {
    union { unsigned u; float f; } v; v.u = ((unsigned)(unsigned short)s) << 16;
    return v.f;
}
static __device__ __forceinline__ void gload_lds16(const void* g, void* l) {
    __builtin_amdgcn_global_load_lds(
        (__attribute__((address_space(1))) void*)g,
        (__attribute__((address_space(3))) void*)l, 16, 0, 0);
}

// ---------------------------------------------------------------------------
// Kernel 0: fp32 -> bf16. x -> xb; {Wq,Wk,Wv} -> Wcat[1536][512]; Wo -> Wob.
// grid 1536, block 256
// ---------------------------------------------------------------------------
__global__ __launch_bounds__(256) void convert_kernel(
    const float* __restrict__ x, const float* __restrict__ Wq,
    const float* __restrict__ Wk, const float* __restrict__ Wv,
    const float* __restrict__ Wo,
    short* __restrict__ xb, short* __restrict__ Wcat, short* __restrict__ Wob)
{
    const int u = blockIdx.x * 256 + threadIdx.x;
    const float* src; short* dst;
    if (u < 262144) {
        src = x + (size_t)u * 8; dst = xb + (size_t)u * 8;
    } else {
        const int v = u - 262144;
        const int o = (v & 32767) * 8;
        if (v < 32768)       { src = Wq + o; dst = Wcat + o; }
        else if (v < 65536)  { src = Wk + o; dst = Wcat + 262144 + o; }
        else if (v < 98304)  { src = Wv + o; dst = Wcat + 524288 + o; }
        else                 { src = Wo + o; dst = Wob + o; }
    }
    const float4 a = *(const float4*)src;
    const float4 b = *(const float4*)(src + 4);
    *(bf16x8*)dst = (bf16x8){f2bf(a.x), f2bf(a.y), f2bf(a.z), f2bf(a.w),
                             f2bf(b.x), f2bf(b.y), f2bf(b.z), f2bf(b.w)};
}

// ---------------------------------------------------------------------------
// Kernel 1: B-stationary barrier-free QKV projection.
// Block (nblk, mg): B-panel = Wcat rows nblk*64..+64 (one head of Q/K/V),
// full K=512, staged ONCE into 64 KB LDS (XOR-chunk swizzle). Then each wave
// free-runs: 2 m-subtiles x 16 K-steps, A-frags loaded straight from global
// (L2-hot) -- NO barriers in the hot loop. Epilogue on a bounce tile aliased
// over the dead B-panel: softmax->Qs / elu->Kbf+Ktb / ->Vt.
// grid (24, 32), block 256 (4 waves), 64 KB LDS, 2 blocks/CU.
// ---------------------------------------------------------------------------
__global__ __launch_bounds__(256, 2) void proj_bstat_kernel(
    const short* __restrict__ xb, const short* __restrict__ Wcat,
    short* __restrict__ Qs, short* __restrict__ Kbf,
    short* __restrict__ Ktb, short* __restrict__ Vt)
{
    __shared__ short BL[64 * 512];   // 64 KB B-panel; bounce tile aliases later
    const int nblk = blockIdx.x;                 // 0..23
    const int which = nblk >> 3, head = nblk & 7;
    const int n0 = nblk * 64;
    const int m0 = blockIdx.y * 128;
    const int tid = threadIdx.x;
    const int lane = tid & 63, w = tid >> 6;
    const int fr = lane & 15, fg = lane >> 4;
    const int b = m0 >> 11, t0 = m0 & (T_SEQ - 1);
    const int bh = b * NH + head;

    // ---- stage B-panel once: 16 iters, one row per wave per iter ----
    // LDS[row][ck] = Wcat[n0+row][ck ^ (row&7)]  (16B chunks, pre-swizzled src)
    #pragma unroll
    for (int it = 0; it < 16; ++it) {
        const int row = it * 4 + w;
        gload_lds16(Wcat + (size_t)(n0 + row) * DIMM + (lane ^ (row & 7)) * 8,
                    &BL[row * 512]);
    }
    asm volatile("s_waitcnt vmcnt(0)" ::: "memory");
    __syncthreads();

    // ---- free-running M-loop: 2 subtiles x 16 K-steps, no barriers ----
    f32x4 acc[2][4] = {};
    #pragma unroll
    for (int ms = 0; ms < 2; ++ms) {
        const int mrow = m0 + ms * 64 + w * 16 + fr;
        const short* ap = xb + (size_t)mrow * DIMM + fg * 8;
        #pragma unroll
        for (int kk = 0; kk < 16; ++kk) {
            const bf16x8 af = *(const bf16x8*)(ap + kk * 32);
            #pragma unroll
            for (int j = 0; j < 4; ++j) {
                const int cc = (kk * 4 + fg) ^ (fr & 7);
                const bf16x8 bfr = *(const bf16x8*)&BL[(j * 16 + fr) * 512 + cc * 8];
                acc[ms][j] = __builtin_amdgcn_mfma_f32_16x16x32_bf16(af, bfr, acc[ms][j], 0, 0, 0);
            }
        }
    }
    __syncthreads();   // all waves done reading BL; safe to alias

    // ---- bounce acc -> Cs[128][66] (elu+1 fused for K) ----
    short* Cs = BL;
    #pragma unroll
    for (int ms = 0; ms < 2; ++ms)
        #pragma unroll
        for (int j = 0; j < 4; ++j)
            #pragma unroll
            for (int reg = 0; reg < 4; ++reg) {
                float val = acc[ms][j][reg];
                if (which == 1) val = (val > 0.f) ? (val + 1.f) : __expf(val);
                Cs[(ms * 64 + w * 16 + fg * 4 + reg) * BCST + j * 16 + fr] = f2bf(val);
            }
    __syncthreads();

    if (which == 0) {
        if (tid < 128) {
            const int r = tid;
            const unsigned* cr = (const unsigned*)&Cs[r * BCST];   // 32 u32
            unsigned u[32];
            #pragma unroll
            for (int s = 0; s < 32; s++) u[s] = cr[s];
            float mx = -1e30f;
            #pragma unroll
            for (int s = 0; s < 32; s++) {
                mx = fmaxf(mx, bf2f((short)(u[s] & 0xffff)));
                mx = fmaxf(mx, bf2f((short)(u[s] >> 16)));
            }
            float sum = 0.f;
            #pragma unroll
            for (int s = 0; s < 32; s++) {
                sum += __expf(bf2f((short)(u[s] & 0xffff)) - mx);
                sum += __expf(bf2f((short)(u[s] >> 16)) - mx);
            }
            const float inv = 1.f / sum;
            short* qp = Qs + ((size_t)bh * T_SEQ + t0 + r) * HD;
            #pragma unroll
            for (int g = 0; g < 8; g++) {
                bf16x8 o;
                #pragma unroll
                for (int k = 0; k < 4; k++) {
                    const unsigned uv = u[g * 4 + k];
                    o[2 * k]     = f2bf(__expf(bf2f((short)(uv & 0xffff)) - mx) * inv);
                    o[2 * k + 1] = f2bf(__expf(bf2f((short)(uv >> 16)) - mx) * inv);
                }
                *(bf16x8*)(qp + g * 8) = o;
            }
        }
    } else if (which == 1) {
        // Kbf row copies (already elu'd in Cs)
        if (tid < 128) {
            const int r = tid;
            const unsigned* cr = (const unsigned*)&Cs[r * BCST];
            short* kp = Kbf + ((size_t)bh * T_SEQ + t0 + r) * HD;
            #pragma unroll
            for (int g = 0; g < 8; g++) {
                bf16x8 o;
                #pragma unroll
                for (int k = 0; k < 4; k++) {
                    const unsigned uv = cr[g * 4 + k];
                    o[2 * k]     = (short)(uv & 0xffff);
                    o[2 * k + 1] = (short)(uv >> 16);
                }
                *(bf16x8*)(kp + g * 8) = o;
            }
        }
        // Ktb transpose: thread (col, q) -> rows q*32..+32 of column col
        {
            const int col = tid & 63, q = tid >> 6;
            short* ktp = Ktb + ((size_t)bh * HD + col) * T_SEQ + t0 + q * 32;
            #pragma unroll
            for (int s = 0; s < 4; s++) {
                bf16x8 o;
                #pragma unroll
                for (int k = 0; k < 8; k++) o[k] = Cs[(q * 32 + s * 8 + k) * BCST + col];
                *(bf16x8*)(ktp + s * 8) = o;
            }
        }
    } else {
        // Vt transpose
        const int col = tid & 63, q = tid >> 6;
        short* vtp = Vt + ((size_t)bh * HD + col) * T_SEQ + t0 + q * 32;
        #pragma unroll
        for (int s = 0; s < 4; s++) {
            bf16x8 o;
            #pragma unroll
            for (int k = 0; k < 8; k++) o[k] = Cs[(q * 32 + s * 8 + k) * BCST + col];
            *(bf16x8*)(vtp + s * 8) = o;
        }
    }
}

// ---------------------------------------------------------------------------
// Kernel 2: per-chunk sums via MFMA: S[e][d] = sum_t Vt[e][t]*Kt[d][t]; ksum[d].
// grid 512, block 256
// ---------------------------------------------------------------------------
__global__ __launch_bounds__(256) void chunk_sum_kernel(
    const short* __restrict__ Ktb, const short* __restrict__ Vt,
    float* __restrict__ Schunk, float* __restrict__ kchunk)
{
    __shared__ short VtL[64 * LDST];
    __shared__ short KtL[64 * LDST];
    __shared__ float ksp[4][64];
    const int bh = blockIdx.x >> 5, c = blockIdx.x & 31;
    const int tid = threadIdx.x;
    const int lane = tid & 63, w = tid >> 6;
    const int fr = lane & 15, fg = lane >> 4;
    #pragma unroll
    for (int it = 0; it < 2; it++) {
        const int qi = it * 256 + tid;
        const int r = qi >> 3, c8 = (qi & 7) * 8;
        *(bf16x8*)&VtL[r * LDST + c8] =
            *(const bf16x8*)(Vt + ((size_t)(bh * HD) + r) * T_SEQ + c * CHUNK + c8);
        *(bf16x8*)&KtL[r * LDST + c8] =
            *(const bf16x8*)(Ktb + ((size_t)(bh * HD) + r) * T_SEQ + c * CHUNK + c8);
    }
    __syncthreads();
    f32x4 acc[4] = {};
    #pragma unroll
    for (int ks = 0; ks < 2; ks++) {
        const bf16x8 av = *(const bf16x8*)&VtL[(w * 16 + fr) * LDST + ks * 32 + fg * 8];
        #pragma unroll
        for (int j = 0; j < 4; j++) {
            const bf16x8 bk = *(const bf16x8*)&KtL[(j * 16 + fr) * LDST + ks * 32 + fg * 8];
            acc[j] = __builtin_amdgcn_mfma_f32_16x16x32_bf16(av, bk, acc[j], 0, 0, 0);
        }
    }
    float* Sout = Schunk + ((size_t)bh * NCHUNK + c) * 4096;
    #pragma unroll
    for (int j = 0; j < 4; j++)
        #pragma unroll
        for (int reg = 0; reg < 4; reg++)
            Sout[(w * 16 + fg * 4 + reg) * 64 + j * 16 + fr] = acc[j][reg];
    float ps = 0.f;
    #pragma unroll
    for (int t = 0; t < 16; t++) ps += bf2f(KtL[lane * LDST + w * 16 + t]);
    ksp[w][lane] = ps;
    __syncthreads();
    if (tid < 64)
        kchunk[((size_t)bh * NCHUNK + c) * 64 + tid] =
            ksp[0][tid] + ksp[1][tid] + ksp[2][tid] + ksp[3][tid];
}

// ---------------------------------------------------------------------------
// Kernel 3: exclusive prefix over 32 chunks; one scan per thread. grid 260
// ---------------------------------------------------------------------------
__global__ __launch_bounds__(256) void scan_kernel(float* __restrict__ Schunk,
                                                   float* __restrict__ kchunk)
{
    const int gid = blockIdx.x * 256 + threadIdx.x;
    if (blockIdx.x < 256) {
        const int bh = gid >> 12, i = gid & 4095;
        float run = 0.f;
        float* p = Schunk + (size_t)bh * NCHUNK * 4096 + i;
        for (int c = 0; c < NCHUNK; c++) { const float tv = p[c * 4096]; p[c * 4096] = run; run += tv; }
    } else {
        const int idx = gid - 65536;
        const int bh = idx >> 6, d = idx & 63;
        float run = 0.f;
        float* p = kchunk + (size_t)bh * NCHUNK * 64 + d;
        for (int c = 0; c < NCHUNK; c++) { const float tv = p[c * 64]; p[c * 64] = run; run += tv; }
    }
}

// ---------------------------------------------------------------------------
// Kernel 4: intra-chunk via MFMA.
// qn = Qs/(Ksum+eps); A = tril(qn.K^T); attn = qn.Sp^T + A.V^T  (bf16 out)
// grid 512, block 256
// ---------------------------------------------------------------------------
__global__ __launch_bounds__(256) void intra_kernel(
    const short* __restrict__ Qs, const short* __restrict__ Kbf,
    const short* __restrict__ Vt, const float* __restrict__ Schunk,
    const float* __restrict__ kchunk, short* __restrict__ attnb)
{
    __shared__ short B1[64 * LDST];
    __shared__ short B2[64 * LDST];
    __shared__ short KL[64 * LDST];
    __shared__ short VtL[64 * LDST];
    __shared__ short QnL[64 * LDST];
    __shared__ float gsum[4][64];
    __shared__ float kpre[64];
    const int bh = blockIdx.x >> 5, c = blockIdx.x & 31;
    const int tid = threadIdx.x;
    const int lane = tid & 63, w = tid >> 6;
    const int fr = lane & 15, fg = lane >> 4;
    const size_t tdbase = ((size_t)bh * T_SEQ + c * CHUNK) * HD;
    #pragma unroll
    for (int it = 0; it < 2; it++) {
        const int qi = it * 256 + tid;
        const int r = qi >> 3, c8 = (qi & 7) * 8;
        *(bf16x8*)&B1[r * LDST + c8]  = *(const bf16x8*)(Qs + tdbase + r * HD + c8);
        *(bf16x8*)&KL[r * LDST + c8]  = *(const bf16x8*)(Kbf + tdbase + r * HD + c8);
        *(bf16x8*)&VtL[r * LDST + c8] =
            *(const bf16x8*)(Vt + ((size_t)(bh * HD) + r) * T_SEQ + c * CHUNK + c8);
    }
    {
        const float* Sp = Schunk + ((size_t)bh * NCHUNK + c) * 4096;
        #pragma unroll
        for (int it = 0; it < 4; it++) {
            const int qi = it * 256 + tid;
            const int r = qi >> 4, c4 = (qi & 15) * 4;
            const float4 v = *(const float4*)(Sp + r * 64 + c4);
            *(s16x4*)&B2[r * LDST + c4] = (s16x4){f2bf(v.x), f2bf(v.y), f2bf(v.z), f2bf(v.w)};
        }
    }
    if (tid < 64) kpre[tid] = kchunk[((size_t)bh * NCHUNK + c) * 64 + tid];
    __syncthreads();
    {
        float s = 0.f;
        #pragma unroll
        for (int t = 0; t < 16; t++) s += bf2f(KL[(w * 16 + t) * LDST + lane]);
        gsum[w][lane] = s;
    }
    __syncthreads();
    {
        float run = kpre[lane];
        for (int gg = 0; gg < w; gg++) run += gsum[gg][lane];
        #pragma unroll
        for (int t0 = 0; t0 < 16; t0++) {
            const int t = w * 16 + t0;
            run += bf2f(KL[t * LDST + lane]);
            const float qv = bf2f(B1[t * LDST + lane]);
            QnL[t * LDST + lane] = f2bf(qv / (run + EPSV));
        }
    }
    __syncthreads();
    {
        f32x4 a1[4] = {};
        #pragma unroll
        for (int ks = 0; ks < 2; ks++) {
            const bf16x8 aq = *(const bf16x8*)&QnL[(w * 16 + fr) * LDST + ks * 32 + fg * 8];
            #pragma unroll
            for (int j = 0; j < 4; j++) {
                const bf16x8 bk = *(const bf16x8*)&KL[(j * 16 + fr) * LDST + ks * 32 + fg * 8];
                a1[j] = __builtin_amdgcn_mfma_f32_16x16x32_bf16(aq, bk, a1[j], 0, 0, 0);
            }
        }
        const int trow = w * 16 + fg * 4;
        #pragma unroll
        for (int j = 0; j < 4; j++)
            #pragma unroll
            for (int reg = 0; reg < 4; reg++) {
                const int t = trow + reg, s = j * 16 + fr;
                B1[t * LDST + s] = (s <= t) ? f2bf(a1[j][reg]) : (short)0;
            }
    }
    __syncthreads();
    {
        f32x4 a2[4] = {};
        #pragma unroll
        for (int ks = 0; ks < 2; ks++) {
            const bf16x8 aq = *(const bf16x8*)&QnL[(w * 16 + fr) * LDST + ks * 32 + fg * 8];
            const bf16x8 aa = *(const bf16x8*)&B1[(w * 16 + fr) * LDST + ks * 32 + fg * 8];
            #pragma unroll
            for (int j = 0; j < 4; j++) {
                const bf16x8 bs = *(const bf16x8*)&B2[(j * 16 + fr) * LDST + ks * 32 + fg * 8];
                const bf16x8 bv = *(const bf16x8*)&VtL[(j * 16 + fr) * LDST + ks * 32 + fg * 8];
                a2[j] = __builtin_amdgcn_mfma_f32_16x16x32_bf16(aq, bs, a2[j], 0, 0, 0);
                a2[j] = __builtin_amdgcn_mfma_f32_16x16x32_bf16(aa, bv, a2[j], 0, 0, 0);
            }
        }
        short* ap = attnb + tdbase;
        const int trow = w * 16 + fg * 4;
        #pragma unroll
        for (int j = 0; j < 4; j++)
            #pragma unroll
            for (int reg = 0; reg < 4; reg++)
                ap[(trow + reg) * HD + j * 16 + fr] = f2bf(a2[j][reg]);
    }
}

// ---------------------------------------------------------------------------
// Kernel 5: out = attn(permuted) @ Wo^T + bo, 64x64 tile. grid (64,8), 256
// ---------------------------------------------------------------------------
__global__ __launch_bounds__(256) void outproj_mfma_kernel(
    const short* __restrict__ attnb, const short* __restrict__ Wob,
    const float* __restrict__ bo, float* __restrict__ out)
{
    __shared__ short As[64 * 64];
    __shared__ short Bs[64 * 64];
    const int m0 = blockIdx.x * 64;
    const int n0 = blockIdx.y * 64;
    const int tid = threadIdx.x;
    const int lane = tid & 63, w = tid >> 6;
    const int fr = lane & 15, fg = lane >> 4;
    const int lr = lane >> 3, lc = (lane & 7) * 8;
    const int b = m0 >> 11, tbase = m0 & (T_SEQ - 1);
    f32x4 acc[4] = {};
    for (int k0 = 0; k0 < DIMM; k0 += 64) {
        const int h = k0 >> 6;
        #pragma unroll
        for (int it = 0; it < 2; it++) {
            const int r0 = w * 16 + it * 8;
            gload_lds16(attnb + (((size_t)(b * NH + h)) * T_SEQ + tbase + r0 + lr) * HD + lc,
                        &As[r0 * 64]);
            gload_lds16(Wob + (size_t)(n0 + r0 + lr) * DIMM + k0 + lc, &Bs[r0 * 64]);
        }
        __syncthreads();
        #pragma unroll
        for (int ks = 0; ks < 2; ks++) {
            const bf16x8 af = *(const bf16x8*)&As[(w * 16 + fr) * 64 + ks * 32 + fg * 8];
            #pragma unroll
            for (int j = 0; j < 4; j++) {
                const bf16x8 bfr = *(const bf16x8*)&Bs[(j * 16 + fr) * 64 + ks * 32 + fg * 8];
                acc[j] = __builtin_amdgcn_mfma_f32_16x16x32_bf16(af, bfr, acc[j], 0, 0, 0);
            }
        }
        __syncthreads();
    }
    #pragma unroll
    for (int j = 0; j < 4; j++)
        #pragma unroll
        for (int reg = 0; reg < 4; reg++) {
            const int m = m0 + w * 16 + fg * 4 + reg;
            const int n = n0 + j * 16 + fr;
            out[(size_t)m * DIMM + n] = acc[j][reg] + bo[n];
        }
}

// ---------------------------------------------------------------------------
extern "C" void kernel_launch(void* const* d_in, const int* in_sizes, int n_in,
                              void* d_out, int out_size, void* d_ws, size_t ws_size,
                              hipStream_t stream)
{
    const float* x  = (const float*)d_in[0];
    const float* Wq = (const float*)d_in[1];
    const float* Wk = (const float*)d_in[2];
    const float* Wv = (const float*)d_in[3];
    const float* Wo = (const float*)d_in[4];
    const float* bo = (const float*)d_in[5];
    float* out = (float*)d_out;

    const size_t NELEM = (size_t)BB * T_SEQ * DIMM;   // 2,097,152
    short* xb    = (short*)d_ws;                      // [4096][512]
    short* Wcat  = xb + NELEM;                        // [1536][512]
    short* Wob   = Wcat + 786432;                     // [512][512]
    short* Qs    = Wob + 262144;
    short* Kbf   = Qs + NELEM;
    short* Ktb   = Kbf + NELEM;
    short* Vt    = Ktb + NELEM;
    short* attnb = Vt + NELEM;
    float* Schunk = (float*)(attnb + NELEM);                    // [bh][c][e][d]
    float* kchunk = Schunk + (size_t)BB * NH * NCHUNK * 4096;   // [bh][c][d]

    convert_kernel<<<dim3(1536), 256, 0, stream>>>(x, Wq, Wk, Wv, Wo, xb, Wcat, Wob);
    proj_bstat_kernel<<<dim3(24, 32), 256, 0, stream>>>(xb, Wcat, Qs, Kbf, Ktb, Vt);
    chunk_sum_kernel<<<dim3(BB * NH * NCHUNK), 256, 0, stream>>>(Ktb, Vt, Schunk, kchunk);
    scan_kernel<<<dim3(260), 256, 0, stream>>>(Schunk, kchunk);
    intra_kernel<<<dim3(BB * NH * NCHUNK), 256, 0, stream>>>(Qs, Kbf, Vt, Schunk, kchunk, attnb);
    outproj_mfma_kernel<<<dim3(64, 8), 256, 0, stream>>>(attnb, Wob, bo, out);
}